// Round 10
// baseline (355.722 us; speedup 1.0000x reference)
//
#include <hip/hip_runtime.h>

// 6-point periodic stencil + DGPE ODE RHS on a 192^3 lattice.
// v8 (resubmit — prior run was an infra failure, not a kernel verdict).
//     float4 per thread (4 z-elems) + asm-pinned MLP + plain stores.
//     This is v2 with both confounds removed: (a) v2's loads were
//     re-batched by the compiler into ~6-VGPR groups with vmcnt(0) drains
//     (VGPR_Count=32 proved it) — here all 21 loads are volatile asm,
//     genuinely outstanding together; (b) v2 used nontemporal stores,
//     which v4-vs-v7 suggests cost a few % — here stores are plain.
//     Discriminator: if wide loads at full MLP beat v7's scalar loads at
//     full MLP, per-instruction request-rate was a real term; if flat,
//     every structural axis is falsified and v7 is the plateau.
// Neighbor index arrays unused (arithmetic indices).

#define LDIM 192
#define LSQ  (LDIM * LDIM)          // 36864
#define NTOT (LDIM * LDIM * LDIM)   // 7077888
#define NQ   (NTOT / 4)             // 1769472 float4 cells
#define LSQ4 (LSQ / 4)              // 9216  (plane stride in float4)
#define LD4  (LDIM / 4)             // 48    (row stride in float4)

typedef float floatx4 __attribute__((ext_vector_type(4)));

#define GLOAD4(dst, ptr) \
    asm volatile("global_load_dwordx4 %0, %1, off" : "=v"(dst) : "v"(ptr))
#define GLOAD1(dst, ptr) \
    asm volatile("global_load_dword %0, %1, off" : "=v"(dst) : "v"(ptr))

__global__ __launch_bounds__(256) void dgpe_kernel(
    const float* __restrict__ y,
    const float* __restrict__ Jarr,
    const float* __restrict__ aniso,
    const float* __restrict__ gam,
    const float* __restrict__ hdx,
    const float* __restrict__ hdy,
    const float* __restrict__ beta,
    const float* __restrict__ edis,
    float* __restrict__ out)
{
    const int q = blockIdx.x * blockDim.x + threadIdx.x;

    // decompose q (float4 index) = a*9216 + b*48 + cq
    const unsigned uq  = (unsigned)q;
    const unsigned a   = uq / LSQ4;
    const unsigned rem = uq - a * LSQ4;
    const unsigned b   = rem / LD4;
    const unsigned cq  = rem - b * LD4;

    // periodic neighbors, float4 index space for x/y dirs
    const int xm4 = (a == 0)        ? q + (LDIM - 1) * LSQ4 : q - LSQ4;
    const int xp4 = (a == LDIM - 1) ? q - (LDIM - 1) * LSQ4 : q + LSQ4;
    const int ym4 = (b == 0)        ? q + (LDIM - 1) * LD4  : q - LD4;
    const int yp4 = (b == LDIM - 1) ? q - (LDIM - 1) * LD4  : q + LD4;

    // z-direction edge scalars (float index space)
    const int i   = q * 4;
    const int zmi = (cq == 0)       ? i + (LDIM - 1) : i - 1;  // elem 0's z-minus
    const int zpi = (cq == LD4 - 1) ? i - (LDIM - 4) : i + 4;  // elem 3's z-plus

    const floatx4* __restrict__ x4 = (const floatx4*)y;
    const floatx4* __restrict__ p4 = (const floatx4*)(y + NTOT);
    const float*   __restrict__ x  = y;
    const float*   __restrict__ p  = y + NTOT;

    // ---- 21 loads, ALL in flight before one waitcnt; fields first ----
    floatx4 xc, xxm, xxp, xym, xyp;
    floatx4 pc, pxm, pxp, pym, pyp;
    float   xzm, xzp, pzm, pzp;
    floatx4 Jv, anv, gv, edv, btv, hxv, hyv;

    GLOAD4(xc,  x4 + q);
    GLOAD4(xxm, x4 + xm4);
    GLOAD4(xxp, x4 + xp4);
    GLOAD4(xym, x4 + ym4);
    GLOAD4(xyp, x4 + yp4);
    GLOAD1(xzm, x + zmi);
    GLOAD1(xzp, x + zpi);

    GLOAD4(pc,  p4 + q);
    GLOAD4(pxm, p4 + xm4);
    GLOAD4(pxp, p4 + xp4);
    GLOAD4(pym, p4 + ym4);
    GLOAD4(pyp, p4 + yp4);
    GLOAD1(pzm, p + zmi);
    GLOAD1(pzp, p + zpi);

    GLOAD4(Jv,  ((const floatx4*)Jarr ) + q);
    GLOAD4(anv, ((const floatx4*)aniso) + q);
    GLOAD4(gv,  ((const floatx4*)gam  ) + q);
    GLOAD4(edv, ((const floatx4*)edis ) + q);
    GLOAD4(btv, ((const floatx4*)beta ) + q);
    GLOAD4(hxv, ((const floatx4*)hdx  ) + q);
    GLOAD4(hyv, ((const floatx4*)hdy  ) + q);

    asm volatile("s_waitcnt vmcnt(0)" ::: "memory");
    __builtin_amdgcn_sched_barrier(0);   // rule 18: no consumer hoists above

    // z neighbors: interior ones come from the center float4 (register shuffle)
    const floatx4 xzmv = {xzm,   xc.x,  xc.y,  xc.z};
    const floatx4 xzpv = {xc.y,  xc.z,  xc.w,  xzp};
    const floatx4 pzmv = {pzm,   pc.x,  pc.y,  pc.z};
    const floatx4 pzpv = {pc.y,  pc.z,  pc.w,  pzp};

    floatx4 odx, odp;
#pragma unroll
    for (int e = 0; e < 4; ++e) {
        const float Ji = Jv[e];
        const float an = anv[e];
        const float xi = xc[e];
        const float pi = pc[e];

        const float xL = Ji * (xxm[e] + xxp[e] + xym[e] + xyp[e]
                               + an * (xzmv[e] + xzpv[e]));
        const float yL = Ji * (pxm[e] + pxp[e] + pym[e] + pyp[e]
                               + an * (pzmv[e] + pzpv[e]));

        const float g  = gv[e];
        const float ed = edv[e];
        const float bt = btv[e];

        const float r2    = xi * xi + pi * pi;
        const float cross = xL * pi - yL * xi;

        odx[e] =  g * pi * cross + ed * pi - yL + hyv[e] + bt * r2 * pi;
        odp[e] = -g * xi * cross - ed * xi + xL - hxv[e] - bt * r2 * xi;
    }

    floatx4* __restrict__ o4 = (floatx4*)out;
    o4[q]      = odx;   // plain stores (nt hurt: v4 vs v7)
    o4[q + NQ] = odp;
}

extern "C" void kernel_launch(void* const* d_in, const int* in_sizes, int n_in,
                              void* d_out, int out_size, void* d_ws, size_t ws_size,
                              hipStream_t stream) {
    // d_in: 0=t, 1=y, 2=J, 3=anisotropy, 4=gamma, 5=h_dis_x, 6=h_dis_y,
    //       7=beta, 8=e_disorder, 9..14=neighbor index arrays (unused)
    const float* y_    = (const float*)d_in[1];
    const float* Jarr  = (const float*)d_in[2];
    const float* aniso = (const float*)d_in[3];
    const float* gam   = (const float*)d_in[4];
    const float* hdx   = (const float*)d_in[5];
    const float* hdy   = (const float*)d_in[6];
    const float* beta  = (const float*)d_in[7];
    const float* edis  = (const float*)d_in[8];
    float* out = (float*)d_out;

    const int threads = 256;
    const int blocks  = NQ / threads;  // 6912, exact
    dgpe_kernel<<<blocks, threads, 0, stream>>>(y_, Jarr, aniso, gam, hdx, hdy,
                                                beta, edis, out);
}